// Round 5
// baseline (763.578 us; speedup 1.0000x reference)
//
#include <hip/hip_runtime.h>

typedef unsigned short ushort_t;
typedef __attribute__((ext_vector_type(8))) short short8;
typedef __attribute__((ext_vector_type(8))) unsigned short ushort8;
typedef __attribute__((ext_vector_type(4))) float floatx4;
typedef __attribute__((ext_vector_type(16))) float floatx16;

#define M_TOT 32768   // B*S
#define KDIM  1024    // folded reduction dim (x part only)
#define N3    6144    // 3 * 2048 (q,k,v outputs)
#define D2    2048
#define NBATCH 1024
#define SSEQ   32

__device__ __forceinline__ ushort_t f2bf(float f){
  unsigned int u = __builtin_bit_cast(unsigned int, f);
  u += 0x7fffu + ((u >> 16) & 1u);           // RNE
  return (ushort_t)(u >> 16);
}

__device__ __forceinline__ void gld16(const void* g, void* l){
  __builtin_amdgcn_global_load_lds((__attribute__((address_space(1))) void*)g,
                                   (__attribute__((address_space(3))) void*)l,
                                   16, 0, 0);
}

__device__ __forceinline__ void barrier_raw(){
  asm volatile("" ::: "memory");
  __builtin_amdgcn_s_barrier();
  asm volatile("" ::: "memory");
}
#define WAIT_VM(N)  asm volatile("s_waitcnt vmcnt(" #N ")" ::: "memory")
#define WAIT_LGKM0  asm volatile("s_waitcnt lgkmcnt(0)" ::: "memory")

// ---------------- prep kernels ----------------

__global__ void k_cast_x(const float* __restrict__ x, ushort_t* __restrict__ xb){
  size_t i = (size_t)blockIdx.x * 256 + threadIdx.x;   // one thread per 8 elems
  const float4* s = (const float4*)x;
  float4 a = s[2*i], b = s[2*i+1];
  ushort8 o;
  o[0]=f2bf(a.x); o[1]=f2bf(a.y); o[2]=f2bf(a.z); o[3]=f2bf(a.w);
  o[4]=f2bf(b.x); o[5]=f2bf(b.y); o[6]=f2bf(b.z); o[7]=f2bf(b.w);
  *(ushort8*)(xb + 8*i) = o;
}

// W_all[row=p*2048+n][j] = W_p[n][j] for j<1024  (left half of each weight row)
__global__ void k_cast_w(const float* __restrict__ Wq, const float* __restrict__ Wk,
                         const float* __restrict__ Wv, ushort_t* __restrict__ Wall){
  int i = blockIdx.x * 256 + threadIdx.x;
  int e = i * 8;
  int row = e >> 10, col = e & 1023;
  int p = row >> 11, n = row & 2047;
  const float* W = (p==0) ? Wq : (p==1) ? Wk : Wv;
  const float4* s = (const float4*)(W + (size_t)n*2048 + col);
  float4 a = s[0], b = s[1];
  ushort8 o;
  o[0]=f2bf(a.x); o[1]=f2bf(a.y); o[2]=f2bf(a.z); o[3]=f2bf(a.w);
  o[4]=f2bf(b.x); o[5]=f2bf(b.y); o[6]=f2bf(b.z); o[7]=f2bf(b.w);
  *(ushort8*)(Wall + (size_t)row*1024 + col) = o;
}

__global__ void k_cast_wfc(const float* __restrict__ Wfc, ushort_t* __restrict__ wfcb){
  int i = blockIdx.x * 256 + threadIdx.x;
  const float4* s = (const float4*)Wfc;
  float4 a = s[2*i], b = s[2*i+1];
  ushort8 o;
  o[0]=f2bf(a.x); o[1]=f2bf(a.y); o[2]=f2bf(a.z); o[3]=f2bf(a.w);
  o[4]=f2bf(b.x); o[5]=f2bf(b.y); o[6]=f2bf(b.z); o[7]=f2bf(b.w);
  *(ushort8*)(wfcb + 8*(size_t)i) = o;
}

// bias_all[s][p*2048+n] = b_p[n] + sum_j pe[s][j] * W_p[n][1024+j]   (fp32)
__global__ void k_bias(const float* __restrict__ pe,
                       const float* __restrict__ Wq, const float* __restrict__ bq,
                       const float* __restrict__ Wk, const float* __restrict__ bk,
                       const float* __restrict__ Wv, const float* __restrict__ bv,
                       float* __restrict__ bias_all){
  int t = threadIdx.x;
  int ni = t & 7, s = t >> 3;
  int col = blockIdx.x * 8 + ni;           // 0..6143
  int p = col >> 11, n = col & 2047;
  const float* W  = (p==0) ? Wq : (p==1) ? Wk : Wv;
  const float* bb = (p==0) ? bq : (p==1) ? bk : bv;
  const float4* w4 = (const float4*)(W + (size_t)n*2048 + 1024);
  const float4* p4 = (const float4*)(pe + (size_t)s*1024);
  float acc = 0.f;
  #pragma unroll 4
  for (int j = 0; j < 256; ++j){
    float4 w = w4[j], q = p4[j];
    acc += w.x*q.x + w.y*q.y + w.z*q.z + w.w*q.w;
  }
  bias_all[(size_t)s*N3 + col] = acc + bb[n];
}

// ---------------- QKV GEMM: 256x256 tile, BK=64, 8 waves (2x4), 8-phase, 32x32x16 MFMA ----------------
// qkv[m][n] = sum_k xb[m][k]*Wall[n][k] + bias_all[m%32][n]
// LDS: [dbuf 2][half 2][...] per operand; swizzle chunk ^= row&7 (0 conflicts, verified r2/r4).
__global__ __launch_bounds__(512, 1) void k_gemm(const ushort_t* __restrict__ xb,
                                                 const ushort_t* __restrict__ Wall,
                                                 const float* __restrict__ bias_all,
                                                 ushort_t* __restrict__ qkv){
  __shared__ alignas(16) ushort_t sA[2][2*128*64];   // [dbuf][half*8192 + linear chunks]
  __shared__ alignas(16) ushort_t sB[2][2*128*64];

  const int t = threadIdx.x, w = t >> 6, l = t & 63;
  const int wr = w >> 2, wc = w & 3;          // 2x4 wave grid -> wave owns 128x64 of C
  const int l31 = l & 31, lh = l >> 5;
  const int m0 = blockIdx.x * 256;
  const int n0 = blockIdx.y * 256;

  const ushort_t* gA = xb   + (size_t)m0 * KDIM;
  const ushort_t* gB = Wall + (size_t)n0 * KDIM;

  floatx16 acc[4][2] = {};   // [mh*2+mf][nh], 32x32 frags

  // ---- staging (same as r4, verified): one half-tile = 1024 x 16B chunks; 2 gld16/thread ----
  auto STAGE_A = [&](int kt, int d, int h){
    #pragma unroll
    for (int j = 0; j < 2; ++j){
      int p = j*512 + t;
      int wr_ = p >> 9, ridx = (p >> 3) & 63, c = (p & 7) ^ (ridx & 7);
      int R = wr_*128 + h*64 + ridx;
      gld16(gA + (size_t)R*KDIM + kt*64 + c*8, &sA[d][(size_t)h*8192 + (size_t)(j*512 + w*64)*8]);
    }
  };
  auto STAGE_B = [&](int kt, int d, int h){
    #pragma unroll
    for (int j = 0; j < 2; ++j){
      int p = j*512 + t;
      int wc_ = p >> 8, ridx = (p >> 3) & 31, c = (p & 7) ^ (ridx & 7);
      int R = wc_*64 + h*32 + ridx;
      gld16(gB + (size_t)R*KDIM + kt*64 + c*8, &sB[d][(size_t)h*8192 + (size_t)(j*512 + w*64)*8]);
    }
  };

  short8 a[8], b0[4], b1[4];   // a[mf*4+ks]; b[ks]
  auto RDA = [&](int d, int mh){      // 8 ds_read_b128
    #pragma unroll
    for (int mf = 0; mf < 2; ++mf)
      #pragma unroll
      for (int ks = 0; ks < 4; ++ks){
        int ridx = mf*32 + l31;
        int ch = (ks*2 + lh) ^ (ridx & 7);
        a[mf*4+ks] = *(const short8*)&sA[d][(size_t)mh*8192 + (size_t)(wr*512 + ridx*8 + ch)*8];
      }
  };
  auto RDB = [&](int d, int nh, short8* b){   // 4 ds_read_b128
    #pragma unroll
    for (int ks = 0; ks < 4; ++ks){
      int ridx = l31;
      int ch = (ks*2 + lh) ^ (ridx & 7);
      b[ks] = *(const short8*)&sB[d][(size_t)nh*8192 + (size_t)(wc*256 + ridx*8 + ch)*8];
    }
  };
  auto MM = [&](int mh, int nh, const short8* b){   // 8 MFMA 32x32x16
    #pragma unroll
    for (int mf = 0; mf < 2; ++mf)
      #pragma unroll
      for (int ks = 0; ks < 4; ++ks)
        acc[mh*2+mf][nh] = __builtin_amdgcn_mfma_f32_32x32x16_bf16(
            a[mf*4+ks], b[ks], acc[mh*2+mf][nh], 0, 0, 0);
  };

  #define MIDBAR  do { barrier_raw(); WAIT_LGKM0; __builtin_amdgcn_sched_barrier(0); } while(0)
  #define PRIO_MM(mh, nh, b) do { __builtin_amdgcn_s_setprio(1); MM(mh, nh, b); __builtin_amdgcn_s_setprio(0); } while(0)

  // prologue: tau0 (all 4 halves) + tau1 {A.h0, B.h1}; drain to last-4; barrier
  STAGE_A(0,0,0); STAGE_B(0,0,1); STAGE_A(0,0,1); STAGE_B(0,0,0);
  STAGE_A(1,1,0); STAGE_B(1,1,1);
  WAIT_VM(4);
  barrier_raw();

  const int NI = KDIM / 128;   // 8 iters, 2 K-tiles each
  for (int i = 0; i < NI; ++i){
    const int t1 = 2*i+1, t2 = 2*i+2, t3 = 2*i+3;
    const bool pre = (i < NI-1);

    // P1: Q(mh0,nh0) of tau0; stage tau1 {A.h1, B.h0} -> dbuf1
    RDA(0,0); RDB(0,0,b0);
    STAGE_A(t1,1,1); STAGE_B(t1,1,0);
    MIDBAR; PRIO_MM(0,0,b0);
    barrier_raw();
    // P2: Q(mh0,nh1)
    RDB(0,1,b1);
    MIDBAR; PRIO_MM(0,1,b1);
    barrier_raw();
    // P3: Q(mh1,nh1); stage tau2 A.h0 -> dbuf0
    RDA(0,1);
    if (pre) STAGE_A(t2,0,0);
    MIDBAR; PRIO_MM(1,1,b1);
    barrier_raw();
    // P4: Q(mh1,nh0); stage tau2 B.h1 -> dbuf0; counted vmcnt before end-bar
    if (pre) STAGE_B(t2,0,1);
    MIDBAR; PRIO_MM(1,0,b0);
    if (pre) { WAIT_VM(4); } else { WAIT_VM(0); }
    barrier_raw();

    // P5: Q(mh0,nh0) of tau1; stage tau2 {A.h1, B.h0} -> dbuf0
    RDA(1,0); RDB(1,0,b0);
    if (pre){ STAGE_A(t2,0,1); STAGE_B(t2,0,0); }
    MIDBAR; PRIO_MM(0,0,b0);
    barrier_raw();
    // P6: Q(mh0,nh1)
    RDB(1,1,b1);
    MIDBAR; PRIO_MM(0,1,b1);
    barrier_raw();
    // P7: Q(mh1,nh1); stage tau3 A.h0 -> dbuf1
    RDA(1,1);
    if (pre) STAGE_A(t3,1,0);
    MIDBAR; PRIO_MM(1,1,b1);
    barrier_raw();
    // P8: Q(mh1,nh0); stage tau3 B.h1 -> dbuf1; counted vmcnt
    if (pre) STAGE_B(t3,1,1);
    MIDBAR; PRIO_MM(1,0,b0);
    if (pre) { WAIT_VM(4); }
    barrier_raw();
  }

  // epilogue: 32x32 C/D: col = l&31, row = (reg&3) + 8*(reg>>2) + 4*(l>>5)
  #pragma unroll
  for (int mi = 0; mi < 4; ++mi){
    #pragma unroll
    for (int nh = 0; nh < 2; ++nh){
      #pragma unroll
      for (int reg = 0; reg < 16; ++reg){
        int rloc = (reg & 3) + 8*(reg >> 2) + 4*lh;
        int row = m0 + wr*128 + mi*32 + rloc;
        int col = n0 + wc*64 + nh*32 + l31;
        float v = acc[mi][nh][reg] + bias_all[(size_t)(rloc & 31)*N3 + col];
        qkv[(size_t)row*N3 + col] = f2bf(v);
      }
    }
  }
  #undef MIDBAR
  #undef PRIO_MM
}

// ---------------- fused attention tail: one d-loop for q.k^T AND v.Wfc^T ----------------
// one block per batch; 256 threads; swizzled LDS staging (chunk ^= row&15 within 256B rows)
__global__ __launch_bounds__(256) void k_attn(const ushort_t* __restrict__ qkv,
                                              const ushort_t* __restrict__ wfcb,
                                              const float* __restrict__ bfc,
                                              float* __restrict__ out){
  __shared__ float attn[32*32];
  __shared__ alignas(16) ushort_t sq[32*128];
  __shared__ alignas(16) ushort_t sk[32*128];
  __shared__ alignas(16) ushort_t sv[32*128];
  __shared__ alignas(16) ushort_t sw[32*128];
  __shared__ float red[4];
  const int b = blockIdx.x;
  const int t = threadIdx.x, w = t >> 6, l = t & 63;
  const int qh = w >> 1, kh = w & 1;
  const int lr = l & 15, lg = l >> 4;

  // staging decode: round r covers chunks p = r*256 + t; row=p>>4, gcol=((p&15)^(row&15))*8
  int srow[2], scol[2];
  #pragma unroll
  for (int r = 0; r < 2; ++r){
    int p = r*256 + t;
    srow[r] = p >> 4;
    scol[r] = ((p & 15) ^ (srow[r] & 15)) * 8;
  }
  const ushort_t* base = qkv + (size_t)(b*32)*N3;

  floatx4 aq = {0.f, 0.f, 0.f, 0.f};   // logits quadrant
  floatx4 ap = {0.f, 0.f, 0.f, 0.f};   // P = v @ wfc^T quadrant
  for (int d0 = 0; d0 < D2; d0 += 128){
    #pragma unroll
    for (int r = 0; r < 2; ++r){
      gld16(base + (size_t)srow[r]*N3 + d0 + scol[r],        sq + (size_t)(r*256 + w*64)*8);
      gld16(base + (size_t)srow[r]*N3 + D2 + d0 + scol[r],   sk + (size_t)(r*256 + w*64)*8);
      gld16(base + (size_t)srow[r]*N3 + 2*D2 + d0 + scol[r], sv + (size_t)(r*256 + w*64)*8);
      gld16(wfcb + (size_t)srow[r]*D2 + d0 + scol[r],        sw + (size_t)(r*256 + w*64)*8);
    }
    __syncthreads();
    #pragma unroll
    for (int kc = 0; kc < 4; ++kc){
      int rowq = qh*16 + lr, rowk = kh*16 + lr;
      short8 vq = *(const short8*)(sq + rowq*128 + (((kc*4+lg) ^ (rowq & 15))*8));
      short8 vk = *(const short8*)(sk + rowk*128 + (((kc*4+lg) ^ (rowk & 15))*8));
      aq = __builtin_amdgcn_mfma_f32_16x16x32_bf16(vq, vk, aq, 0, 0, 0);
      short8 vv = *(const short8*)(sv + rowk*128 + (((kc*4+lg) ^ (rowk & 15))*8));
      short8 vw = *(const short8*)(sw + rowq*128 + (((kc*4+lg) ^ (rowq & 15))*8));
      ap = __builtin_amdgcn_mfma_f32_16x16x32_bf16(vv, vw, ap, 0, 0, 0);
    }
    __syncthreads();
  }

  const float rs = 0.022097086912079608f;  // 1/sqrt(2048)
  #pragma unroll
  for (int r = 0; r < 4; ++r){
    int qi = qh*16 + lg*4 + r, ki = kh*16 + lr;
    attn[qi*32 + ki] = aq[r] * rs;
  }
  __syncthreads();

  // softmax over query axis (column-wise), t<32 handles column ki=t
  if (t < 32){
    int ki = t;
    float mx = -1e30f;
    #pragma unroll 4
    for (int qi = 0; qi < 32; ++qi) mx = fmaxf(mx, attn[qi*32 + ki]);
    float sm = 0.f;
    #pragma unroll 4
    for (int qi = 0; qi < 32; ++qi){
      float e = __expf(attn[qi*32 + ki] - mx);
      attn[qi*32 + ki] = e; sm += e;
    }
    float inv = 1.0f / sm;
    #pragma unroll 4
    for (int qi = 0; qi < 32; ++qi) attn[qi*32 + ki] *= inv;
  }
  __syncthreads();

  // ap holds P[ki][qi] (A=v rows ki, B=wfc rows qi): row=ki, col=qi
  float sum = 0.f;
  #pragma unroll
  for (int r = 0; r < 4; ++r){
    int ki = kh*16 + lg*4 + r, qi = qh*16 + lr;
    sum += ap[r] * attn[qi*32 + ki];
  }
  #pragma unroll
  for (int off = 32; off > 0; off >>= 1) sum += __shfl_down(sum, off, 64);
  if (l == 0) red[w] = sum;
  __syncthreads();
  if (t == 0) out[b] = red[0] + red[1] + red[2] + red[3] + bfc[0];
}

// ---------------- host ----------------
extern "C" void kernel_launch(void* const* d_in, const int* in_sizes, int n_in,
                              void* d_out, int out_size, void* d_ws, size_t ws_size,
                              hipStream_t stream) {
  const float* x   = (const float*)d_in[0];
  const float* pe  = (const float*)d_in[1];
  const float* Wq  = (const float*)d_in[2];
  const float* bq  = (const float*)d_in[3];
  const float* Wk  = (const float*)d_in[4];
  const float* bk  = (const float*)d_in[5];
  const float* Wv  = (const float*)d_in[6];
  const float* bv  = (const float*)d_in[7];
  const float* Wfc = (const float*)d_in[8];
  const float* bfc = (const float*)d_in[9];
  float* out = (float*)d_out;
  (void)in_sizes; (void)n_in; (void)out_size; (void)ws_size;

  char* ws = (char*)d_ws;
  size_t off = 0;
  auto alloc = [&](size_t bytes) -> void* {
    void* p = ws + off;
    off += (bytes + 255) & ~(size_t)255;
    return p;
  };
  ushort_t* xb       = (ushort_t*)alloc((size_t)M_TOT * KDIM * 2);   //  64 MiB
  ushort_t* Wall     = (ushort_t*)alloc((size_t)N3 * KDIM * 2);      //  12 MiB
  float*    bias_all = (float*)   alloc((size_t)SSEQ * N3 * 4);      // 768 KiB
  ushort_t* wfcb     = (ushort_t*)alloc((size_t)SSEQ * D2 * 2);      // 128 KiB
  ushort_t* qkv      = (ushort_t*)alloc((size_t)M_TOT * N3 * 2);     // 384 MiB

  k_cast_x  <<<dim3(M_TOT*KDIM/8/256), dim3(256), 0, stream>>>(x, xb);
  k_cast_w  <<<dim3(N3*KDIM/8/256),    dim3(256), 0, stream>>>(Wq, Wk, Wv, Wall);
  k_cast_wfc<<<dim3(SSEQ*D2/8/256),    dim3(256), 0, stream>>>(Wfc, wfcb);
  k_bias    <<<dim3(N3/8),             dim3(256), 0, stream>>>(pe, Wq, bq, Wk, bk, Wv, bv, bias_all);
  k_gemm    <<<dim3(M_TOT/256, N3/256), dim3(512), 0, stream>>>(xb, Wall, bias_all, qkv);
  k_attn    <<<dim3(NBATCH),           dim3(256), 0, stream>>>(qkv, wfcb, bfc, out);
}

// Round 6
// 735.031 us; speedup vs baseline: 1.0388x; 1.0388x over previous
//
#include <hip/hip_runtime.h>

typedef unsigned short ushort_t;
typedef __attribute__((ext_vector_type(8))) short short8;
typedef __attribute__((ext_vector_type(8))) unsigned short ushort8;
typedef __attribute__((ext_vector_type(4))) float floatx4;

#define M_TOT 32768   // B*S
#define KDIM  1024    // folded reduction dim (x part only)
#define N3    6144    // 3 * 2048 (q,k,v outputs)
#define D2    2048
#define NBATCH 1024
#define SSEQ   32

__device__ __forceinline__ ushort_t f2bf(float f){
  unsigned int u = __builtin_bit_cast(unsigned int, f);
  u += 0x7fffu + ((u >> 16) & 1u);           // RNE
  return (ushort_t)(u >> 16);
}

__device__ __forceinline__ void gld16(const void* g, void* l){
  __builtin_amdgcn_global_load_lds((__attribute__((address_space(1))) void*)g,
                                   (__attribute__((address_space(3))) void*)l,
                                   16, 0, 0);
}

__device__ __forceinline__ void barrier_raw(){
  asm volatile("" ::: "memory");
  __builtin_amdgcn_s_barrier();
  asm volatile("" ::: "memory");
}
#define WAIT_VM(N)  asm volatile("s_waitcnt vmcnt(" #N ")" ::: "memory")
#define WAIT_LGKM0  asm volatile("s_waitcnt lgkmcnt(0)" ::: "memory")

// ---------------- prep kernels ----------------

__global__ void k_cast_x(const float* __restrict__ x, ushort_t* __restrict__ xb){
  size_t i = (size_t)blockIdx.x * 256 + threadIdx.x;   // one thread per 8 elems
  const float4* s = (const float4*)x;
  float4 a = s[2*i], b = s[2*i+1];
  ushort8 o;
  o[0]=f2bf(a.x); o[1]=f2bf(a.y); o[2]=f2bf(a.z); o[3]=f2bf(a.w);
  o[4]=f2bf(b.x); o[5]=f2bf(b.y); o[6]=f2bf(b.z); o[7]=f2bf(b.w);
  *(ushort8*)(xb + 8*i) = o;
}

// W_all[row=p*2048+n][j] = W_p[n][j] for j<1024  (left half of each weight row)
__global__ void k_cast_w(const float* __restrict__ Wq, const float* __restrict__ Wk,
                         const float* __restrict__ Wv, ushort_t* __restrict__ Wall){
  int i = blockIdx.x * 256 + threadIdx.x;
  int e = i * 8;
  int row = e >> 10, col = e & 1023;
  int p = row >> 11, n = row & 2047;
  const float* W = (p==0) ? Wq : (p==1) ? Wk : Wv;
  const float4* s = (const float4*)(W + (size_t)n*2048 + col);
  float4 a = s[0], b = s[1];
  ushort8 o;
  o[0]=f2bf(a.x); o[1]=f2bf(a.y); o[2]=f2bf(a.z); o[3]=f2bf(a.w);
  o[4]=f2bf(b.x); o[5]=f2bf(b.y); o[6]=f2bf(b.z); o[7]=f2bf(b.w);
  *(ushort8*)(Wall + (size_t)row*1024 + col) = o;
}

__global__ void k_cast_wfc(const float* __restrict__ Wfc, ushort_t* __restrict__ wfcb){
  int i = blockIdx.x * 256 + threadIdx.x;
  const float4* s = (const float4*)Wfc;
  float4 a = s[2*i], b = s[2*i+1];
  ushort8 o;
  o[0]=f2bf(a.x); o[1]=f2bf(a.y); o[2]=f2bf(a.z); o[3]=f2bf(a.w);
  o[4]=f2bf(b.x); o[5]=f2bf(b.y); o[6]=f2bf(b.z); o[7]=f2bf(b.w);
  *(ushort8*)(wfcb + 8*(size_t)i) = o;
}

// bias_all[s][p*2048+n] = b_p[n] + sum_j pe[s][j] * W_p[n][1024+j]   (fp32)
__global__ void k_bias(const float* __restrict__ pe,
                       const float* __restrict__ Wq, const float* __restrict__ bq,
                       const float* __restrict__ Wk, const float* __restrict__ bk,
                       const float* __restrict__ Wv, const float* __restrict__ bv,
                       float* __restrict__ bias_all){
  int t = threadIdx.x;
  int ni = t & 7, s = t >> 3;
  int col = blockIdx.x * 8 + ni;           // 0..6143
  int p = col >> 11, n = col & 2047;
  const float* W  = (p==0) ? Wq : (p==1) ? Wk : Wv;
  const float* bb = (p==0) ? bq : (p==1) ? bk : bv;
  const float4* w4 = (const float4*)(W + (size_t)n*2048 + 1024);
  const float4* p4 = (const float4*)(pe + (size_t)s*1024);
  float acc = 0.f;
  #pragma unroll 4
  for (int j = 0; j < 256; ++j){
    float4 w = w4[j], q = p4[j];
    acc += w.x*q.x + w.y*q.y + w.z*q.z + w.w*q.w;
  }
  bias_all[(size_t)s*N3 + col] = acc + bb[n];
}

// ---------------- QKV GEMM: 256x256 tile, BK=64, 8 waves (2x4), m201-style 8-phase ----------------
// (r4 kernel, verified: 475 us, 0 bank conflicts, MfmaUtil 37.5%)
__global__ __launch_bounds__(512, 1) void k_gemm(const ushort_t* __restrict__ xb,
                                                 const ushort_t* __restrict__ Wall,
                                                 const float* __restrict__ bias_all,
                                                 ushort_t* __restrict__ qkv){
  __shared__ alignas(16) ushort_t sA[2][2*128*64];   // [dbuf][half*8192 + r*64 + c*8]
  __shared__ alignas(16) ushort_t sB[2][2*128*64];

  const int t = threadIdx.x, w = t >> 6, l = t & 63;
  const int wr = w >> 2, wc = w & 3;          // 2x4 wave grid -> wave owns 128x64 of C
  const int lr = l & 15, lg = l >> 4;
  const int m0 = blockIdx.x * 256;
  const int n0 = blockIdx.y * 256;

  const ushort_t* gA = xb   + (size_t)m0 * KDIM;
  const ushort_t* gB = Wall + (size_t)n0 * KDIM;

  floatx4 acc[8][4] = {};   // [mh*4+mi][nh*2+ni]

  auto STAGE_A = [&](int kt, int d, int h){
    #pragma unroll
    for (int j = 0; j < 2; ++j){
      int p = j*512 + t;
      int wr_ = p >> 9, ridx = (p >> 3) & 63, c = (p & 7) ^ (ridx & 7);
      int R = wr_*128 + h*64 + ridx;
      gld16(gA + (size_t)R*KDIM + kt*64 + c*8, &sA[d][(size_t)h*8192 + (size_t)(j*512 + w*64)*8]);
    }
  };
  auto STAGE_B = [&](int kt, int d, int h){
    #pragma unroll
    for (int j = 0; j < 2; ++j){
      int p = j*512 + t;
      int wc_ = p >> 8, ridx = (p >> 3) & 31, c = (p & 7) ^ (ridx & 7);
      int R = wc_*64 + h*32 + ridx;
      gld16(gB + (size_t)R*KDIM + kt*64 + c*8, &sB[d][(size_t)h*8192 + (size_t)(j*512 + w*64)*8]);
    }
  };

  short8 a[8], b0[4], b1[4];
  auto RDA = [&](int d, int mh){      // 8 ds_read_b128
    #pragma unroll
    for (int mi = 0; mi < 4; ++mi)
      #pragma unroll
      for (int ks = 0; ks < 2; ++ks){
        int ch = (ks*4 + lg) ^ (lr & 7);
        a[mi*2+ks] = *(const short8*)&sA[d][(size_t)mh*8192 + (size_t)(wr*64 + mi*16 + lr)*64 + ch*8];
      }
  };
  auto RDB = [&](int d, int nh, short8* b){   // 4 ds_read_b128
    #pragma unroll
    for (int ni = 0; ni < 2; ++ni)
      #pragma unroll
      for (int ks = 0; ks < 2; ++ks){
        int ch = (ks*4 + lg) ^ (lr & 7);
        b[ni*2+ks] = *(const short8*)&sB[d][(size_t)nh*8192 + (size_t)(wc*32 + ni*16 + lr)*64 + ch*8];
      }
  };
  auto MM = [&](int mh, int nh, const short8* b){   // 16 MFMA (one quadrant x K=64)
    #pragma unroll
    for (int mi = 0; mi < 4; ++mi)
      #pragma unroll
      for (int ni = 0; ni < 2; ++ni)
        #pragma unroll
        for (int ks = 0; ks < 2; ++ks)
          acc[mh*4+mi][nh*2+ni] = __builtin_amdgcn_mfma_f32_16x16x32_bf16(
              a[mi*2+ks], b[ni*2+ks], acc[mh*4+mi][nh*2+ni], 0, 0, 0);
  };

  #define MIDBAR  do { barrier_raw(); WAIT_LGKM0; __builtin_amdgcn_sched_barrier(0); } while(0)
  #define PRIO_MM(mh, nh, b) do { __builtin_amdgcn_s_setprio(1); MM(mh, nh, b); __builtin_amdgcn_s_setprio(0); } while(0)

  // prologue: tau0 (all 4 halves) + tau1 {A.h0, B.h1}; drain to last-4; barrier
  STAGE_A(0,0,0); STAGE_B(0,0,1); STAGE_A(0,0,1); STAGE_B(0,0,0);
  STAGE_A(1,1,0); STAGE_B(1,1,1);
  WAIT_VM(4);
  barrier_raw();

  const int NI = KDIM / 128;   // 8 iters, 2 K-tiles each (tau0=2i -> dbuf0, tau1=2i+1 -> dbuf1)
  for (int i = 0; i < NI; ++i){
    const int t1 = 2*i+1, t2 = 2*i+2, t3 = 2*i+3;
    const bool pre = (i < NI-1);

    // P1: Q(mh0,nh0) of tau0; stage tau1 {A.h1, B.h0} -> dbuf1
    RDA(0,0); RDB(0,0,b0);
    STAGE_A(t1,1,1); STAGE_B(t1,1,0);
    MIDBAR; PRIO_MM(0,0,b0);
    barrier_raw();
    // P2: Q(mh0,nh1)
    RDB(0,1,b1);
    MIDBAR; PRIO_MM(0,1,b1);
    barrier_raw();
    // P3: Q(mh1,nh1); stage tau2 A.h0 -> dbuf0 (freed after P2)
    RDA(0,1);
    if (pre) STAGE_A(t2,0,0);
    MIDBAR; PRIO_MM(1,1,b1);
    barrier_raw();
    // P4: Q(mh1,nh0); stage tau2 B.h1 -> dbuf0 (freed after P3); counted vmcnt before end-bar
    if (pre) STAGE_B(t2,0,1);
    MIDBAR; PRIO_MM(1,0,b0);
    if (pre) { WAIT_VM(4); } else { WAIT_VM(0); }
    barrier_raw();

    // P5: Q(mh0,nh0) of tau1; stage tau2 {A.h1, B.h0} -> dbuf0 (freed after P4)
    RDA(1,0); RDB(1,0,b0);
    if (pre){ STAGE_A(t2,0,1); STAGE_B(t2,0,0); }
    MIDBAR; PRIO_MM(0,0,b0);
    barrier_raw();
    // P6: Q(mh0,nh1)
    RDB(1,1,b1);
    MIDBAR; PRIO_MM(0,1,b1);
    barrier_raw();
    // P7: Q(mh1,nh1); stage tau3 A.h0 -> dbuf1 (freed after P6)
    RDA(1,1);
    if (pre) STAGE_A(t3,1,0);
    MIDBAR; PRIO_MM(1,1,b1);
    barrier_raw();
    // P8: Q(mh1,nh0); stage tau3 B.h1 -> dbuf1 (freed after P7); counted vmcnt
    if (pre) STAGE_B(t3,1,1);
    MIDBAR; PRIO_MM(1,0,b0);
    if (pre) { WAIT_VM(4); }
    barrier_raw();
  }

  // epilogue: C/D layout col=lr, row=lg*4+r
  #pragma unroll
  for (int mh = 0; mh < 2; ++mh)
    #pragma unroll
    for (int mi = 0; mi < 4; ++mi)
      #pragma unroll
      for (int nh = 0; nh < 2; ++nh)
        #pragma unroll
        for (int ni = 0; ni < 2; ++ni)
          #pragma unroll
          for (int r = 0; r < 4; ++r){
            int row = m0 + wr*128 + mh*64 + mi*16 + lg*4 + r;
            int col = n0 + wc*64 + nh*32 + ni*16 + lr;
            float v = acc[mh*4+mi][nh*2+ni][r] + bias_all[(size_t)(row & 31)*N3 + col];
            qkv[(size_t)row*N3 + col] = f2bf(v);
          }
  #undef MIDBAR
  #undef PRIO_MM
}

// ---------------- fused attention tail: pipelined, counted-vmcnt ----------------
// one block per batch; 256 threads; 64-d slices, dbuf, raw barriers, vmcnt(4).
// LDS ~36KB -> 4 blocks/CU, all 1024 blocks resident.
__global__ __launch_bounds__(256) void k_attn(const ushort_t* __restrict__ qkv,
                                              const ushort_t* __restrict__ wfcb,
                                              const float* __restrict__ bfc,
                                              float* __restrict__ out){
  __shared__ alignas(16) ushort_t sq[2][32*64];   // 4KB each buffer
  __shared__ alignas(16) ushort_t sk[2][32*64];
  __shared__ alignas(16) ushort_t sv[2][32*64];
  __shared__ alignas(16) ushort_t sw[2][32*64];
  __shared__ float attn[32*32];
  __shared__ float red[4];
  const int b = blockIdx.x;
  const int t = threadIdx.x, w = t >> 6, l = t & 63;
  const int qh = w >> 1, kh = w & 1;
  const int lr = l & 15, lg = l >> 4;

  // staging: thread t stages LDS chunk t of each operand; row=t>>3, gchunk=(t&7)^(row&7)
  const int srow = t >> 3;
  const int scol = ((t & 7) ^ (srow & 7)) * 8;
  const ushort_t* base = qkv + (size_t)(b*32)*N3;
  const ushort_t* gq = base + (size_t)srow*N3 + scol;
  const ushort_t* gw = wfcb + (size_t)srow*D2 + scol;

  auto STAGE = [&](int s){
    const int d = s & 1;
    const ushort_t* g0 = gq + s*64;
    gld16(g0,          &sq[d][(w*64)*8]);
    gld16(g0 + D2,     &sk[d][(w*64)*8]);
    gld16(g0 + 2*D2,   &sv[d][(w*64)*8]);
    gld16(gw + s*64,   &sw[d][(w*64)*8]);
  };
  auto RD = [&](const ushort_t* s_, int row, int kc) -> short8 {
    int ch = (kc*4 + lg) ^ (row & 7);
    return *(const short8*)(s_ + (size_t)(row*8 + ch)*8);
  };

  floatx4 aq = {0.f, 0.f, 0.f, 0.f};   // logits quadrant
  floatx4 ap = {0.f, 0.f, 0.f, 0.f};   // P = v @ wfc^T quadrant
  const int rowq = qh*16 + lr, rowk = kh*16 + lr;

  STAGE(0); STAGE(1);                  // 8 loads in flight
  const int NS = D2 / 64;              // 32 slices
  for (int s = 0; s < NS; ++s){
    const int d = s & 1;
    if (s == NS-1) { WAIT_VM(0); } else { WAIT_VM(4); }   // slice s landed (s+1 stays in flight)
    barrier_raw();
    #pragma unroll
    for (int kc = 0; kc < 2; ++kc){
      short8 vq = RD(sq[d], rowq, kc);
      short8 vk = RD(sk[d], rowk, kc);
      aq = __builtin_amdgcn_mfma_f32_16x16x32_bf16(vq, vk, aq, 0, 0, 0);
      short8 vv = RD(sv[d], rowk, kc);
      short8 vw = RD(sw[d], rowq, kc);
      ap = __builtin_amdgcn_mfma_f32_16x16x32_bf16(vv, vw, ap, 0, 0, 0);
    }
    WAIT_LGKM0;
    barrier_raw();                     // all waves done reading buf d
    if (s + 2 < NS) STAGE(s + 2);      // overwrite buf d with slice s+2
  }

  const float rs = 0.022097086912079608f;  // 1/sqrt(2048)
  #pragma unroll
  for (int r = 0; r < 4; ++r){
    int qi = qh*16 + lg*4 + r, ki = kh*16 + lr;
    attn[qi*32 + ki] = aq[r] * rs;
  }
  __syncthreads();

  // softmax over query axis (column-wise), t<32 handles column ki=t
  if (t < 32){
    int ki = t;
    float mx = -1e30f;
    #pragma unroll 4
    for (int qi = 0; qi < 32; ++qi) mx = fmaxf(mx, attn[qi*32 + ki]);
    float sm = 0.f;
    #pragma unroll 4
    for (int qi = 0; qi < 32; ++qi){
      float e = __expf(attn[qi*32 + ki] - mx);
      attn[qi*32 + ki] = e; sm += e;
    }
    float inv = 1.0f / sm;
    #pragma unroll 4
    for (int qi = 0; qi < 32; ++qi) attn[qi*32 + ki] *= inv;
  }
  __syncthreads();

  // ap holds P[ki][qi] (A=v rows ki, B=wfc rows qi): row=ki, col=qi
  float sum = 0.f;
  #pragma unroll
  for (int r = 0; r < 4; ++r){
    int ki = kh*16 + lg*4 + r, qi = qh*16 + lr;
    sum += ap[r] * attn[qi*32 + ki];
  }
  #pragma unroll
  for (int off = 32; off > 0; off >>= 1) sum += __shfl_down(sum, off, 64);
  if (l == 0) red[w] = sum;
  __syncthreads();
  if (t == 0) out[b] = red[0] + red[1] + red[2] + red[3] + bfc[0];
}

// ---------------- host ----------------
extern "C" void kernel_launch(void* const* d_in, const int* in_sizes, int n_in,
                              void* d_out, int out_size, void* d_ws, size_t ws_size,
                              hipStream_t stream) {
  const float* x   = (const float*)d_in[0];
  const float* pe  = (const float*)d_in[1];
  const float* Wq  = (const float*)d_in[2];
  const float* bq  = (const float*)d_in[3];
  const float* Wk  = (const float*)d_in[4];
  const float* bk  = (const float*)d_in[5];
  const float* Wv  = (const float*)d_in[6];
  const float* bv  = (const float*)d_in[7];
  const float* Wfc = (const float*)d_in[8];
  const float* bfc = (const float*)d_in[9];
  float* out = (float*)d_out;
  (void)in_sizes; (void)n_in; (void)out_size; (void)ws_size;

  char* ws = (char*)d_ws;
  size_t off = 0;
  auto alloc = [&](size_t bytes) -> void* {
    void* p = ws + off;
    off += (bytes + 255) & ~(size_t)255;
    return p;
  };
  ushort_t* xb       = (ushort_t*)alloc((size_t)M_TOT * KDIM * 2);   //  64 MiB
  ushort_t* Wall     = (ushort_t*)alloc((size_t)N3 * KDIM * 2);      //  12 MiB
  float*    bias_all = (float*)   alloc((size_t)SSEQ * N3 * 4);      // 768 KiB
  ushort_t* wfcb     = (ushort_t*)alloc((size_t)SSEQ * D2 * 2);      // 128 KiB
  ushort_t* qkv      = (ushort_t*)alloc((size_t)M_TOT * N3 * 2);     // 384 MiB

  k_cast_x  <<<dim3(M_TOT*KDIM/8/256), dim3(256), 0, stream>>>(x, xb);
  k_cast_w  <<<dim3(N3*KDIM/8/256),    dim3(256), 0, stream>>>(Wq, Wk, Wv, Wall);
  k_cast_wfc<<<dim3(SSEQ*D2/8/256),    dim3(256), 0, stream>>>(Wfc, wfcb);
  k_bias    <<<dim3(N3/8),             dim3(256), 0, stream>>>(pe, Wq, bq, Wk, bk, Wv, bv, bias_all);
  k_gemm    <<<dim3(M_TOT/256, N3/256), dim3(512), 0, stream>>>(xb, Wall, bias_all, qkv);
  k_attn    <<<dim3(NBATCH),           dim3(256), 0, stream>>>(qkv, wfcb, bfc, out);
}